// Round 1
// baseline (2328.838 us; speedup 1.0000x reference)
//
#include <hip/hip_runtime.h>
#include <stdint.h>

#define B_ 32
#define T_ 32
#define HH 28
#define WW 28
#define F_ 48
#define U_ 8
#define NFRM (B_*T_)      // 1024 frames
#define NPIX (HH*WW)      // 784 pixels per frame
#define EPSV 1e-3f

__device__ __forceinline__ float bflo(unsigned int packed) {
    union { unsigned int i; float f; } v; v.i = packed << 16; return v.f;
}
__device__ __forceinline__ float bfhi(unsigned int packed) {
    union { unsigned int i; float f; } v; v.i = packed & 0xFFFF0000u; return v.f;
}
__device__ __forceinline__ unsigned short f2bf(float f) {
    union { float f; unsigned int i; } v; v.f = f;
    unsigned int r = v.i + 0x7FFFu + ((v.i >> 16) & 1u);
    return (unsigned short)(r >> 16);
}

// ---------------------------------------------------------------------------
// Kernel 1: conv1 (1 -> 48) + ReLU, write bf16
// one thread = one (frame, pixel), computes all 48 output channels
// ---------------------------------------------------------------------------
__global__ __launch_bounds__(256) void conv1_kernel(
    const float* __restrict__ x, const float* __restrict__ w1,
    const float* __restrict__ b1, unsigned short* __restrict__ out)
{
    __shared__ float sW[9 * 48];
    __shared__ float sB[48];
    int tid = threadIdx.x;
    for (int i = tid; i < 9 * 48; i += 256) sW[i] = w1[i];
    if (tid < 48) sB[tid] = b1[tid];
    __syncthreads();

    int gid = blockIdx.x * 256 + tid;          // 0 .. 802815
    int n = gid / NPIX, p = gid % NPIX;
    int y = p / WW, xx = p % WW;
    const float* xf = x + (size_t)n * NPIX;

    float xin[9];
    #pragma unroll
    for (int dy = 0; dy < 3; dy++) {
        #pragma unroll
        for (int dx = 0; dx < 3; dx++) {
            int yy = y + dy - 1, xc = xx + dx - 1;
            bool ok = (yy >= 0 && yy < HH && xc >= 0 && xc < WW);
            xin[dy * 3 + dx] = ok ? xf[yy * WW + xc] : 0.0f;
        }
    }
    float acc[48];
    #pragma unroll
    for (int c = 0; c < 48; c++) acc[c] = sB[c];
    #pragma unroll
    for (int t = 0; t < 9; t++) {
        float xv = xin[t];
        #pragma unroll
        for (int c = 0; c < 48; c++) acc[c] += xv * sW[t * 48 + c];
    }
    unsigned int* op = (unsigned int*)(out + (size_t)gid * 48);
    #pragma unroll
    for (int c = 0; c < 24; c++) {
        unsigned int lo = f2bf(fmaxf(acc[2 * c], 0.0f));
        unsigned int hi = f2bf(fmaxf(acc[2 * c + 1], 0.0f));
        op[c] = lo | (hi << 16);
    }
}

// ---------------------------------------------------------------------------
// Kernels 2/3: conv (48 -> 48) + ReLU.  One block per frame.
// Whole frame staged in LDS (bf16), full weights in LDS (fp32).
// POOL=false: write bf16 activations.  POOL=true: fuse BN1 + global avg pool.
// ---------------------------------------------------------------------------
template<bool POOL>
__global__ __launch_bounds__(256) void conv48_kernel(
    const unsigned short* __restrict__ in,   // bf16 [NFRM][784][48]
    const float* __restrict__ w,             // [9][48][48]
    const float* __restrict__ bias,          // [48]
    unsigned short* __restrict__ out,        // bf16 (if !POOL)
    float* __restrict__ feats,               // [NFRM][48] (if POOL)
    const float* __restrict__ bn_g, const float* __restrict__ bn_b,
    const float* __restrict__ bn_m, const float* __restrict__ bn_v)
{
    __shared__ alignas(16) float sW[9 * 48 * 48];       // 82944 B
    __shared__ alignas(8)  unsigned short sIn[NPIX * 48]; // 75264 B
    __shared__ float sB[48];
    __shared__ float sRed[4 * 48];

    int tid = threadIdx.x;
    int n = blockIdx.x;

    const uint2* gin = (const uint2*)(in + (size_t)n * NPIX * 48);
    uint2* sin2 = (uint2*)sIn;
    for (int i = tid; i < NPIX * 48 / 4; i += 256) sin2[i] = gin[i];
    const float4* gw = (const float4*)w;
    float4* sw4 = (float4*)sW;
    for (int i = tid; i < 9 * 48 * 48 / 4; i += 256) sw4[i] = gw[i];
    if (tid < 48) sB[tid] = bias[tid];
    __syncthreads();

    float psum[48];
    if (POOL) {
        #pragma unroll
        for (int c = 0; c < 48; c++) psum[c] = 0.0f;
    }

    for (int k = 0; k < 4; k++) {
        int p = tid + k * 256;
        if (p < NPIX) {
            int y = p / WW, xpos = p % WW;
            float acc[48];
            #pragma unroll
            for (int c = 0; c < 48; c++) acc[c] = sB[c];

            for (int dy = 0; dy < 3; dy++) {
                int yy = y + dy - 1;
                if (yy < 0 || yy >= HH) continue;
                for (int dx = 0; dx < 3; dx++) {
                    int xc = xpos + dx - 1;
                    if (xc < 0 || xc >= WW) continue;
                    const unsigned short* ip = &sIn[(yy * WW + xc) * 48];
                    const float* wp = &sW[(dy * 3 + dx) * 48 * 48];
                    #pragma unroll 1
                    for (int c4 = 0; c4 < 12; c4++) {
                        uint2 raw = *(const uint2*)(ip + c4 * 4);
                        float xv0 = bflo(raw.x), xv1 = bfhi(raw.x);
                        float xv2 = bflo(raw.y), xv3 = bfhi(raw.y);
                        #pragma unroll
                        for (int j = 0; j < 4; j++) {
                            float xv = (j == 0) ? xv0 : (j == 1) ? xv1 : (j == 2) ? xv2 : xv3;
                            const float4* w4 = (const float4*)(wp + (c4 * 4 + j) * 48);
                            #pragma unroll
                            for (int q = 0; q < 12; q++) {
                                float4 wv = w4[q];
                                acc[q * 4 + 0] += xv * wv.x;
                                acc[q * 4 + 1] += xv * wv.y;
                                acc[q * 4 + 2] += xv * wv.z;
                                acc[q * 4 + 3] += xv * wv.w;
                            }
                        }
                    }
                }
            }
            if (POOL) {
                #pragma unroll
                for (int c = 0; c < 48; c++) psum[c] += fmaxf(acc[c], 0.0f);
            } else {
                unsigned int* op = (unsigned int*)(out + ((size_t)n * NPIX + p) * 48);
                #pragma unroll
                for (int c = 0; c < 24; c++) {
                    unsigned int lo = f2bf(fmaxf(acc[2 * c], 0.0f));
                    unsigned int hi = f2bf(fmaxf(acc[2 * c + 1], 0.0f));
                    op[c] = lo | (hi << 16);
                }
            }
        }
    }

    if (POOL) {
        #pragma unroll
        for (int c = 0; c < 48; c++) {
            float v = psum[c];
            for (int off = 32; off > 0; off >>= 1) v += __shfl_down(v, off);
            psum[c] = v;
        }
        int lane = tid & 63, wv = tid >> 6;
        if (lane == 0) {
            for (int c = 0; c < 48; c++) sRed[wv * 48 + c] = psum[c];
        }
        __syncthreads();
        if (tid < 48) {
            float s = sRed[tid] + sRed[48 + tid] + sRed[96 + tid] + sRed[144 + tid];
            float mean = s * (1.0f / NPIX);
            float r = rsqrtf(bn_v[tid] + EPSV);
            feats[(size_t)n * 48 + tid] = (mean - bn_m[tid]) * r * bn_g[tid] + bn_b[tid];
        }
    }
}

// ---------------------------------------------------------------------------
// Kernel 4: LSTM over T + BN2 + dense head.  One block per batch element.
// ---------------------------------------------------------------------------
__global__ __launch_bounds__(64) void lstm_kernel(
    const float* __restrict__ feats,
    const float* __restrict__ wf, const float* __restrict__ bfv,
    const float* __restrict__ wi1, const float* __restrict__ bi1,
    const float* __restrict__ wi2, const float* __restrict__ bi2,
    const float* __restrict__ wo, const float* __restrict__ bov,
    const float* __restrict__ g2, const float* __restrict__ b2v,
    const float* __restrict__ m2, const float* __restrict__ v2,
    const float* __restrict__ w_out, const float* __restrict__ b_out,
    float* __restrict__ out)
{
    __shared__ float sW[4][56][8];   // gate order: f, i, g, o
    __shared__ float sBias[4][8];
    __shared__ float sZ[64];
    __shared__ float sGate[4][8];
    __shared__ float sH[8];
    __shared__ float sS[8];
    __shared__ float sK;

    int tid = threadIdx.x;
    int b = blockIdx.x;

    {
        const float* wsrc0 = wf;  const float* wsrc1 = wi1;
        const float* wsrc2 = wi2; const float* wsrc3 = wo;
        for (int i = tid; i < 56 * 8; i += 64) {
            (&sW[0][0][0])[i]           = wsrc0[i];
            (&sW[1][0][0])[i]           = wsrc1[i];
            (&sW[2][0][0])[i]           = wsrc2[i];
            (&sW[3][0][0])[i]           = wsrc3[i];
        }
        if (tid < 8) {
            sBias[0][tid] = bfv[tid];  sBias[1][tid] = bi1[tid];
            sBias[2][tid] = bi2[tid];  sBias[3][tid] = bov[tid];
            float r = rsqrtf(v2[tid] + EPSV);
            sS[tid] = r * g2[tid] * w_out[tid];
            sH[tid] = 0.0f;
        }
        if (tid == 0) {
            float k = b_out[0];
            for (int u = 0; u < 8; u++) {
                float r = rsqrtf(v2[u] + EPSV);
                k += (b2v[u] - m2[u] * r * g2[u]) * w_out[u];
            }
            sK = k;
        }
    }
    __syncthreads();

    float c = 0.0f;   // cell state for lanes tid < 8
    const float* fb = feats + (size_t)b * T_ * 48;

    for (int t = 0; t < T_; t++) {
        if (tid < 48) sZ[tid] = fb[t * 48 + tid];
        else if (tid < 56) sZ[tid] = sH[tid - 48];
        __syncthreads();

        if (tid < 32) {
            int g = tid >> 3, u = tid & 7;
            float a = sBias[g][u];
            #pragma unroll
            for (int k = 0; k < 56; k++) a += sZ[k] * sW[g][k][u];
            float v = (g == 2) ? tanhf(a) : 1.0f / (1.0f + __expf(-a));
            sGate[g][u] = v;
        }
        __syncthreads();

        if (tid < 8) {
            c = sGate[0][tid] * c + sGate[1][tid] * sGate[2][tid];
            float h = sGate[3][tid] * tanhf(c);
            sH[tid] = h;
            float contrib = h * sS[tid];
            contrib += __shfl_xor(contrib, 1);
            contrib += __shfl_xor(contrib, 2);
            contrib += __shfl_xor(contrib, 4);
            if (tid == 0) out[b * T_ + t] = contrib + sK;
        }
        __syncthreads();
    }
}

// ---------------------------------------------------------------------------
extern "C" void kernel_launch(void* const* d_in, const int* in_sizes, int n_in,
                              void* d_out, int out_size, void* d_ws, size_t ws_size,
                              hipStream_t stream)
{
    const float* x    = (const float*)d_in[0];
    const float* w1   = (const float*)d_in[1];
    const float* b1   = (const float*)d_in[2];
    const float* w2   = (const float*)d_in[3];
    const float* b2   = (const float*)d_in[4];
    const float* w3   = (const float*)d_in[5];
    const float* b3   = (const float*)d_in[6];
    const float* bn1g = (const float*)d_in[7];
    const float* bn1b = (const float*)d_in[8];
    const float* bn1m = (const float*)d_in[9];
    const float* bn1v = (const float*)d_in[10];
    const float* wf   = (const float*)d_in[11];
    const float* bf   = (const float*)d_in[12];
    const float* wi1  = (const float*)d_in[13];
    const float* bi1  = (const float*)d_in[14];
    const float* wi2  = (const float*)d_in[15];
    const float* bi2  = (const float*)d_in[16];
    const float* wo   = (const float*)d_in[17];
    const float* bo   = (const float*)d_in[18];
    const float* bn2g = (const float*)d_in[19];
    const float* bn2b = (const float*)d_in[20];
    const float* bn2m = (const float*)d_in[21];
    const float* bn2v = (const float*)d_in[22];
    const float* wout = (const float*)d_in[23];
    const float* bout = (const float*)d_in[24];

    const size_t nAct = (size_t)NFRM * NPIX * 48;   // 38,535,168 elements
    unsigned short* buf1 = (unsigned short*)d_ws;
    unsigned short* buf2 = buf1 + nAct;
    float* feats = (float*)(buf2 + nAct);
    const size_t need = nAct * 2 * 2 + (size_t)NFRM * 48 * 4;
    if (ws_size < need) return;  // visible failure: output stays poisoned

    conv1_kernel<<<NFRM * NPIX / 256, 256, 0, stream>>>(x, w1, b1, buf1);
    conv48_kernel<false><<<NFRM, 256, 0, stream>>>(buf1, w2, b2, buf2, nullptr,
                                                   nullptr, nullptr, nullptr, nullptr);
    conv48_kernel<true><<<NFRM, 256, 0, stream>>>(buf2, w3, b3, nullptr, feats,
                                                  bn1g, bn1b, bn1m, bn1v);
    lstm_kernel<<<B_, 64, 0, stream>>>(feats, wf, bf, wi1, bi1, wi2, bi2, wo, bo,
                                       bn2g, bn2b, bn2m, bn2v, wout, bout,
                                       (float*)d_out);
}

// Round 2
// 291.992 us; speedup vs baseline: 7.9757x; 7.9757x over previous
//
#include <hip/hip_runtime.h>
#include <stdint.h>

#define B_ 32
#define T_ 32
#define HH 28
#define WW 28
#define NFRM 1024
#define NPIX 784
#define EPSV 1e-3f

typedef __attribute__((ext_vector_type(8))) short short8v;
typedef __attribute__((ext_vector_type(4))) float float4v;
typedef __attribute__((ext_vector_type(4))) unsigned int uint4v;

// ---- LDS geometry (bytes) for the MFMA conv kernel ----
#define PIX_STRIDE 96                    // 48 bf16 per pixel
#define IN_BYTES   (NPIX * PIX_STRIDE)   // 75264
#define W_OFF      IN_BYTES
#define W_CO_STRIDE 912                  // 456 bf16 (K 432 -> pad 456; 228 dw % 32 = 4 -> 2-way max)
#define W_HALF     (48 * W_CO_STRIDE)    // 43776
#define W_BYTES    (2 * W_HALF)          // 87552
#define ZERO_OFF   (W_OFF + W_BYTES)     // 162816
#define LDS_BYTES  (ZERO_OFF + 16)       // 162832  (<= 163840)

__device__ __forceinline__ float bflo(unsigned int packed) {
    union { unsigned int i; float f; } v; v.i = packed << 16; return v.f;
}
__device__ __forceinline__ float bfhi(unsigned int packed) {
    union { unsigned int i; float f; } v; v.i = packed & 0xFFFF0000u; return v.f;
}
__device__ __forceinline__ float bf2f(unsigned short u) {
    union { unsigned int i; float f; } v; v.i = ((unsigned int)u) << 16; return v.f;
}
__device__ __forceinline__ unsigned short f2bf(float f) {
    union { float f; unsigned int i; } v; v.f = f;
    unsigned int r = v.i + 0x7FFFu + ((v.i >> 16) & 1u);
    return (unsigned short)(r >> 16);
}

// ---------------------------------------------------------------------------
// Kernel 1: conv1 (1 -> 48) + ReLU, write bf16  (unchanged from R0 baseline)
// ---------------------------------------------------------------------------
__global__ __launch_bounds__(256) void conv1_kernel(
    const float* __restrict__ x, const float* __restrict__ w1,
    const float* __restrict__ b1, unsigned short* __restrict__ out)
{
    __shared__ float sW[9 * 48];
    __shared__ float sB[48];
    int tid = threadIdx.x;
    for (int i = tid; i < 9 * 48; i += 256) sW[i] = w1[i];
    if (tid < 48) sB[tid] = b1[tid];
    __syncthreads();

    int gid = blockIdx.x * 256 + tid;
    int n = gid / NPIX, p = gid % NPIX;
    int y = p / WW, xx = p % WW;
    const float* xf = x + (size_t)n * NPIX;

    float xin[9];
    #pragma unroll
    for (int dy = 0; dy < 3; dy++) {
        #pragma unroll
        for (int dx = 0; dx < 3; dx++) {
            int yy = y + dy - 1, xc = xx + dx - 1;
            bool ok = (yy >= 0 && yy < HH && xc >= 0 && xc < WW);
            xin[dy * 3 + dx] = ok ? xf[yy * WW + xc] : 0.0f;
        }
    }
    float acc[48];
    #pragma unroll
    for (int c = 0; c < 48; c++) acc[c] = sB[c];
    #pragma unroll
    for (int t = 0; t < 9; t++) {
        float xv = xin[t];
        #pragma unroll
        for (int c = 0; c < 48; c++) acc[c] += xv * sW[t * 48 + c];
    }
    unsigned int* op = (unsigned int*)(out + (size_t)gid * 48);
    #pragma unroll
    for (int c = 0; c < 24; c++) {
        unsigned int lo = f2bf(fmaxf(acc[2 * c], 0.0f));
        unsigned int hi = f2bf(fmaxf(acc[2 * c + 1], 0.0f));
        op[c] = lo | (hi << 16);
    }
}

// ---------------------------------------------------------------------------
// Kernels 2/3: conv 48->48 + ReLU as implicit-GEMM MFMA (bf16, split weights).
// One block = one frame. 512 threads = 8 waves; wave w owns M-tiles {w, w+8,..}
// A: frame in LDS, bf16 [784][48], XOR-swizzled (byte bit4 ^= pix bit2).
// B: weights repacked [2(hi/lo)][48 co][456 k] bf16, k = tap*48 + cin.
// POOL=false: write bf16 activations. POOL=true: fuse ReLU+avgpool+BN1.
// ---------------------------------------------------------------------------
template<bool POOL>
__global__ __launch_bounds__(512, 1) void conv48_mfma(
    const unsigned short* __restrict__ in,   // bf16 [NFRM][784][48]
    const float* __restrict__ w,             // fp32 [9][48][48] (HWIO)
    const float* __restrict__ bias,          // [48]
    unsigned short* __restrict__ out,        // bf16 (if !POOL)
    float* __restrict__ feats,               // [NFRM][48] (if POOL)
    const float* __restrict__ bn_g, const float* __restrict__ bn_b,
    const float* __restrict__ bn_m, const float* __restrict__ bn_v)
{
    __shared__ __align__(16) char smem[LDS_BYTES];
    int tid = threadIdx.x;
    int n = blockIdx.x;

    // ---- stage input frame, swizzled, 16B units ----
    const uint4v* gin = (const uint4v*)(in + (size_t)n * NPIX * 48);
    for (int i = tid; i < IN_BYTES / 16; i += 512) {
        int pix = i / 6;
        int ad = (i * 16) ^ ((pix & 4) << 2);
        *(uint4v*)(smem + ad) = gin[i];
    }
    // ---- zero W pad region (k in [432,456)) and the zero page ----
    for (int i = tid; i < 48 * 24; i += 512) {
        int co = i / 24, kk = 432 + (i % 24);
        *(unsigned short*)(smem + W_OFF + co * W_CO_STRIDE + kk * 2) = 0;
        *(unsigned short*)(smem + W_OFF + W_HALF + co * W_CO_STRIDE + kk * 2) = 0;
    }
    if (tid < 4) *(unsigned int*)(smem + ZERO_OFF + tid * 4) = 0;
    // ---- stage weights: hi/lo bf16 split, transposed to [co][k] ----
    for (int i = tid; i < 9 * 48 * 48; i += 512) {
        int k = i / 48, co = i - k * 48;
        float wv = w[i];
        unsigned short hi = f2bf(wv);
        unsigned short lo = f2bf(wv - bf2f(hi));
        *(unsigned short*)(smem + W_OFF + co * W_CO_STRIDE + k * 2) = hi;
        *(unsigned short*)(smem + W_OFF + W_HALF + co * W_CO_STRIDE + k * 2) = lo;
    }
    __syncthreads();

    int lane = tid & 63;
    int wid  = tid >> 6;          // wave 0..7
    int l15  = lane & 15;
    int q    = lane >> 4;
    int qk   = q * 8;

    // per-K-step lane constants (s compile-time via full unroll)
    int tap_s[14], tpo_s[14], t96c_s[14];
    #pragma unroll
    for (int s = 0; s < 14; ++s) {
        int k = s * 32 + qk;
        int tap = k / 48;                 // 0..9 (9 => padded/invalid)
        int kc  = k - tap * 48;
        int c16 = (kc >> 3) << 4;
        int ty = tap / 3, tx = tap - ty * 3;
        tap_s[s]  = tap;
        tpo_s[s]  = ty * 28 + tx;
        t96c_s[s] = tpo_s[s] * 96 + c16;
    }
    int coB[3];
    float biasv[3];
    #pragma unroll
    for (int nt = 0; nt < 3; ++nt) {
        coB[nt] = W_OFF + (nt * 16 + l15) * W_CO_STRIDE + qk * 2;
        biasv[nt] = bias[nt * 16 + l15];
    }

    // per-M-tile lane constants
    float4v acc[7][3];
    int pixb[7], pixb96[7], msk[7];
    #pragma unroll
    for (int mt = 0; mt < 7; ++mt) {
        int tt = wid + mt * 8;
        int p  = tt * 16 + l15;                 // pixel this lane's A-row holds
        int y  = (p * 9363) >> 18;              // p/28, valid p<=895
        int x  = p - y * 28;
        pixb[mt]   = p - 29;                    // (y-1)*28 + (x-1)
        pixb96[mt] = pixb[mt] * 96;
        unsigned my0 = ((unsigned)(y - 1) < 28u) ? 0x007u : 0u;
        unsigned my1 = ((unsigned)(y    ) < 28u) ? 0x038u : 0u;
        unsigned my2 = ((unsigned)(y + 1) < 28u) ? 0x1C0u : 0u;
        unsigned mx0 = ((unsigned)(x - 1) < 28u) ? 0x049u : 0u;
        unsigned mx1 = ((unsigned)(x    ) < 28u) ? 0x092u : 0u;
        unsigned mx2 = ((unsigned)(x + 1) < 28u) ? 0x124u : 0u;
        msk[mt] = (int)((my0 | my1 | my2) & (mx0 | mx1 | mx2));
        #pragma unroll
        for (int nt = 0; nt < 3; ++nt)
            acc[mt][nt] = (float4v){biasv[nt], biasv[nt], biasv[nt], biasv[nt]};
    }

    // ---- main K loop ----
    #pragma unroll
    for (int s = 0; s < 14; ++s) {
        short8v bh0 = *(const short8v*)(smem + coB[0] + s * 64);
        short8v bh1 = *(const short8v*)(smem + coB[1] + s * 64);
        short8v bh2 = *(const short8v*)(smem + coB[2] + s * 64);
        short8v bl0 = *(const short8v*)(smem + coB[0] + W_HALF + s * 64);
        short8v bl1 = *(const short8v*)(smem + coB[1] + W_HALF + s * 64);
        short8v bl2 = *(const short8v*)(smem + coB[2] + W_HALF + s * 64);
        #pragma unroll
        for (int mt = 0; mt < 7; ++mt) {
            int pix = pixb[mt] + tpo_s[s];
            int ad  = (pixb96[mt] + t96c_s[s]) ^ ((pix & 4) << 2);
            ad = ((msk[mt] >> tap_s[s]) & 1) ? ad : ZERO_OFF;
            short8v a = *(const short8v*)(smem + ad);
            acc[mt][0] = __builtin_amdgcn_mfma_f32_16x16x32_bf16(a, bh0, acc[mt][0], 0, 0, 0);
            acc[mt][1] = __builtin_amdgcn_mfma_f32_16x16x32_bf16(a, bh1, acc[mt][1], 0, 0, 0);
            acc[mt][2] = __builtin_amdgcn_mfma_f32_16x16x32_bf16(a, bh2, acc[mt][2], 0, 0, 0);
            acc[mt][0] = __builtin_amdgcn_mfma_f32_16x16x32_bf16(a, bl0, acc[mt][0], 0, 0, 0);
            acc[mt][1] = __builtin_amdgcn_mfma_f32_16x16x32_bf16(a, bl1, acc[mt][1], 0, 0, 0);
            acc[mt][2] = __builtin_amdgcn_mfma_f32_16x16x32_bf16(a, bl2, acc[mt][2], 0, 0, 0);
        }
    }

    // ---- epilogue ----
    if (!POOL) {
        #pragma unroll
        for (int mt = 0; mt < 7; ++mt) {
            int tt = wid + mt * 8;
            if (tt >= 49) continue;                  // pad tiles
            int m0 = tt * 16;
            #pragma unroll
            for (int r = 0; r < 4; ++r) {
                int p = m0 + q * 4 + r;              // C/D row = (lane>>4)*4 + r
                unsigned short* op = out + ((size_t)n * NPIX + p) * 48 + l15;
                op[0]  = f2bf(fmaxf(acc[mt][0][r], 0.0f));
                op[16] = f2bf(fmaxf(acc[mt][1][r], 0.0f));
                op[32] = f2bf(fmaxf(acc[mt][2][r], 0.0f));
            }
        }
    } else {
        float ps0 = 0.0f, ps1 = 0.0f, ps2 = 0.0f;
        #pragma unroll
        for (int mt = 0; mt < 7; ++mt) {
            int tt = wid + mt * 8;
            if (tt >= 49) continue;
            #pragma unroll
            for (int r = 0; r < 4; ++r) {
                ps0 += fmaxf(acc[mt][0][r], 0.0f);
                ps1 += fmaxf(acc[mt][1][r], 0.0f);
                ps2 += fmaxf(acc[mt][2][r], 0.0f);
            }
        }
        ps0 += __shfl_xor(ps0, 16); ps0 += __shfl_xor(ps0, 32);
        ps1 += __shfl_xor(ps1, 16); ps1 += __shfl_xor(ps1, 32);
        ps2 += __shfl_xor(ps2, 16); ps2 += __shfl_xor(ps2, 32);
        __syncthreads();                               // W region now dead; alias it
        float* sRed = (float*)(smem + W_OFF);
        if (lane < 16) {
            sRed[wid * 48 + l15]      = ps0;
            sRed[wid * 48 + 16 + l15] = ps1;
            sRed[wid * 48 + 32 + l15] = ps2;
        }
        __syncthreads();
        if (tid < 48) {
            float s = 0.0f;
            #pragma unroll
            for (int wv = 0; wv < 8; ++wv) s += sRed[wv * 48 + tid];
            float r  = rsqrtf(bn_v[tid] + EPSV);
            float sc = r * bn_g[tid] * (1.0f / 784.0f);
            float sh = bn_b[tid] - bn_m[tid] * r * bn_g[tid];
            feats[(size_t)n * 48 + tid] = s * sc + sh;
        }
    }
}

// ---------------------------------------------------------------------------
// Kernel 4: LSTM over T + BN2 + dense head. (unchanged from R0 baseline)
// ---------------------------------------------------------------------------
__global__ __launch_bounds__(64) void lstm_kernel(
    const float* __restrict__ feats,
    const float* __restrict__ wf, const float* __restrict__ bfv,
    const float* __restrict__ wi1, const float* __restrict__ bi1,
    const float* __restrict__ wi2, const float* __restrict__ bi2,
    const float* __restrict__ wo, const float* __restrict__ bov,
    const float* __restrict__ g2, const float* __restrict__ b2v,
    const float* __restrict__ m2, const float* __restrict__ v2,
    const float* __restrict__ w_out, const float* __restrict__ b_out,
    float* __restrict__ out)
{
    __shared__ float sW[4][56][8];
    __shared__ float sBias[4][8];
    __shared__ float sZ[64];
    __shared__ float sGate[4][8];
    __shared__ float sH[8];
    __shared__ float sS[8];
    __shared__ float sK;

    int tid = threadIdx.x;
    int b = blockIdx.x;

    for (int i = tid; i < 56 * 8; i += 64) {
        (&sW[0][0][0])[i] = wf[i];
        (&sW[1][0][0])[i] = wi1[i];
        (&sW[2][0][0])[i] = wi2[i];
        (&sW[3][0][0])[i] = wo[i];
    }
    if (tid < 8) {
        sBias[0][tid] = bfv[tid];  sBias[1][tid] = bi1[tid];
        sBias[2][tid] = bi2[tid];  sBias[3][tid] = bov[tid];
        float r = rsqrtf(v2[tid] + EPSV);
        sS[tid] = r * g2[tid] * w_out[tid];
        sH[tid] = 0.0f;
    }
    if (tid == 0) {
        float k = b_out[0];
        for (int u = 0; u < 8; u++) {
            float r = rsqrtf(v2[u] + EPSV);
            k += (b2v[u] - m2[u] * r * g2[u]) * w_out[u];
        }
        sK = k;
    }
    __syncthreads();

    float c = 0.0f;
    const float* fb = feats + (size_t)b * T_ * 48;

    for (int t = 0; t < T_; t++) {
        if (tid < 48) sZ[tid] = fb[t * 48 + tid];
        else if (tid < 56) sZ[tid] = sH[tid - 48];
        __syncthreads();

        if (tid < 32) {
            int g = tid >> 3, u = tid & 7;
            float a = sBias[g][u];
            #pragma unroll
            for (int k = 0; k < 56; k++) a += sZ[k] * sW[g][k][u];
            float v = (g == 2) ? tanhf(a) : 1.0f / (1.0f + __expf(-a));
            sGate[g][u] = v;
        }
        __syncthreads();

        if (tid < 8) {
            c = sGate[0][tid] * c + sGate[1][tid] * sGate[2][tid];
            float h = sGate[3][tid] * tanhf(c);
            sH[tid] = h;
            float contrib = h * sS[tid];
            contrib += __shfl_xor(contrib, 1);
            contrib += __shfl_xor(contrib, 2);
            contrib += __shfl_xor(contrib, 4);
            if (tid == 0) out[b * T_ + t] = contrib + sK;
        }
        __syncthreads();
    }
}

// ---------------------------------------------------------------------------
extern "C" void kernel_launch(void* const* d_in, const int* in_sizes, int n_in,
                              void* d_out, int out_size, void* d_ws, size_t ws_size,
                              hipStream_t stream)
{
    const float* x    = (const float*)d_in[0];
    const float* w1   = (const float*)d_in[1];
    const float* b1   = (const float*)d_in[2];
    const float* w2   = (const float*)d_in[3];
    const float* b2   = (const float*)d_in[4];
    const float* w3   = (const float*)d_in[5];
    const float* b3   = (const float*)d_in[6];
    const float* bn1g = (const float*)d_in[7];
    const float* bn1b = (const float*)d_in[8];
    const float* bn1m = (const float*)d_in[9];
    const float* bn1v = (const float*)d_in[10];
    const float* wf   = (const float*)d_in[11];
    const float* bf   = (const float*)d_in[12];
    const float* wi1  = (const float*)d_in[13];
    const float* bi1  = (const float*)d_in[14];
    const float* wi2  = (const float*)d_in[15];
    const float* bi2  = (const float*)d_in[16];
    const float* wo   = (const float*)d_in[17];
    const float* bo   = (const float*)d_in[18];
    const float* bn2g = (const float*)d_in[19];
    const float* bn2b = (const float*)d_in[20];
    const float* bn2m = (const float*)d_in[21];
    const float* bn2v = (const float*)d_in[22];
    const float* wout = (const float*)d_in[23];
    const float* bout = (const float*)d_in[24];

    const size_t nAct = (size_t)NFRM * NPIX * 48;
    unsigned short* buf1 = (unsigned short*)d_ws;
    unsigned short* buf2 = buf1 + nAct;
    float* feats = (float*)(buf2 + nAct);
    const size_t need = nAct * 2 * 2 + (size_t)NFRM * 48 * 4;
    if (ws_size < need) return;

    conv1_kernel<<<NFRM * NPIX / 256, 256, 0, stream>>>(x, w1, b1, buf1);
    conv48_mfma<false><<<NFRM, 512, 0, stream>>>(buf1, w2, b2, buf2, nullptr,
                                                 nullptr, nullptr, nullptr, nullptr);
    conv48_mfma<true><<<NFRM, 512, 0, stream>>>(buf2, w3, b3, nullptr, feats,
                                                bn1g, bn1b, bn1m, bn1v);
    lstm_kernel<<<B_, 64, 0, stream>>>(feats, wf, bf, wi1, bi1, wi2, bi2, wo, bo,
                                       bn2g, bn2b, bn2m, bn2v, wout, bout,
                                       (float*)d_out);
}

// Round 3
// 191.247 us; speedup vs baseline: 12.1771x; 1.5268x over previous
//
#include <hip/hip_runtime.h>
#include <stdint.h>

#define B_ 32
#define T_ 32
#define NPIX 784
#define NFRM 1024
#define EPSV 1e-3f

typedef __attribute__((ext_vector_type(8))) short short8v;
typedef __attribute__((ext_vector_type(4))) float float4v;

// ---- LDS geometry (bytes) ----
// [0, 88064)        : weight region (split-bf16 image; also holds raw x briefly)
// [88064, 163328)   : act region, bf16 [784][48] swizzled (byte^16 when pix&4)
// [163328, 163344)  : zero page
#define W_REGION    88064
#define ACT_OFF     88064
#define ACT_BYTES   75264
#define ZERO_OFF    (ACT_OFF + ACT_BYTES)
#define LDS_TOT     (ZERO_OFF + 16)          // 163344 <= 163840
#define W_CO_STRIDE 912                      // 456 bf16 per out-channel row
#define W_HALF      43776                    // hi block bytes (48*912)
#define WPACK_BYTES 88064                    // per-conv pack in ws (1024B-multiple)

__device__ __forceinline__ float bf2f(unsigned short u) {
    union { unsigned int i; float f; } v; v.i = ((unsigned int)u) << 16; return v.f;
}
__device__ __forceinline__ unsigned short f2bf(float f) {
    union { float f; unsigned int i; } v; v.f = f;
    unsigned int r = v.i + 0x7FFFu + ((v.i >> 16) & 1u);
    return (unsigned short)(r >> 16);
}

// ---------------------------------------------------------------------------
// Kernel 0: pack w2/w3 into the exact byte image the conv kernel stages.
// Per conv (44032 shorts): hi [48 co][456 k], lo at +21888 shorts, slack zeroed.
// k = tap*48 + cin ; k in [432,456) zero-padded.
// ---------------------------------------------------------------------------
__global__ __launch_bounds__(256) void pack_weights(
    const float* __restrict__ w2, const float* __restrict__ w3,
    unsigned short* __restrict__ out)
{
    int idx = blockIdx.x * 256 + threadIdx.x;        // 0 .. 88063
    if (idx >= 2 * 44032) return;
    int conv = idx / 44032;
    int r = idx - conv * 44032;
    const float* w = conv ? w3 : w2;
    unsigned short val = 0;
    if (r < 43776) {
        int half = r / 21888;
        int r2 = r - half * 21888;
        int co = r2 / 456, k = r2 - co * 456;
        if (k < 432) {
            float wv = w[k * 48 + co];
            unsigned short hi = f2bf(wv);
            val = half ? f2bf(wv - bf2f(hi)) : hi;
        }
    }
    out[idx] = val;
}

// ---------------------------------------------------------------------------
// async stage of one weight pack (88064 B) global -> LDS weight region
// ---------------------------------------------------------------------------
__device__ __forceinline__ void stage_w(char* smem, const char* g, int tid) {
    int lane = tid & 63, wid = tid >> 6;
    const char* gl = g + lane * 16;
    for (int c = wid; c < WPACK_BYTES / 1024; c += 8) {
        int off = c * 1024;
        __builtin_amdgcn_global_load_lds(
            (const __attribute__((address_space(1))) unsigned int*)(gl + off),
            (__attribute__((address_space(3))) unsigned int*)(smem + off),
            16, 0, 0);
    }
}

// ---------------------------------------------------------------------------
// Fused conv1 + conv2 + conv3 + ReLU + avgpool + BN1.  One block = one frame.
// 512 threads = 8 waves; wave w owns M-tiles {w, w+8, ...} (49 real tiles).
// ---------------------------------------------------------------------------
#define KLOOP(BH_OFF)                                                          \
    _Pragma("unroll")                                                          \
    for (int s = 0; s < 14; ++s) {                                             \
        short8v bh0 = *(const short8v*)(smem + coB0 + s * 64);                 \
        short8v bh1 = *(const short8v*)(smem + coB1 + s * 64);                 \
        short8v bh2 = *(const short8v*)(smem + coB2 + s * 64);                 \
        short8v bl0 = *(const short8v*)(smem + coB0 + W_HALF + s * 64);        \
        short8v bl1 = *(const short8v*)(smem + coB1 + W_HALF + s * 64);        \
        short8v bl2 = *(const short8v*)(smem + coB2 + W_HALF + s * 64);        \
        _Pragma("unroll")                                                      \
        for (int mt = 0; mt < 7; ++mt) {                                       \
            int pix = pixb[mt] + tpo_s[s];                                     \
            int ad  = (ACT_OFF + pixb96[mt] + t96c_s[s]) ^ ((pix & 4) << 2);   \
            ad = ((msk[mt] >> tap_s[s]) & 1) ? ad : ZERO_OFF;                  \
            short8v a = *(const short8v*)(smem + ad);                          \
            acc[mt][0] = __builtin_amdgcn_mfma_f32_16x16x32_bf16(a, bh0, acc[mt][0], 0, 0, 0); \
            acc[mt][1] = __builtin_amdgcn_mfma_f32_16x16x32_bf16(a, bh1, acc[mt][1], 0, 0, 0); \
            acc[mt][2] = __builtin_amdgcn_mfma_f32_16x16x32_bf16(a, bh2, acc[mt][2], 0, 0, 0); \
            acc[mt][0] = __builtin_amdgcn_mfma_f32_16x16x32_bf16(a, bl0, acc[mt][0], 0, 0, 0); \
            acc[mt][1] = __builtin_amdgcn_mfma_f32_16x16x32_bf16(a, bl1, acc[mt][1], 0, 0, 0); \
            acc[mt][2] = __builtin_amdgcn_mfma_f32_16x16x32_bf16(a, bl2, acc[mt][2], 0, 0, 0); \
        }                                                                      \
    }

__global__ __launch_bounds__(512, 1) void fused_cnn(
    const float* __restrict__ x,              // [NFRM][784] fp32
    const float* __restrict__ w1, const float* __restrict__ b1,
    const float* __restrict__ b2, const float* __restrict__ b3,
    const unsigned short* __restrict__ wpack, // [2][44032] shorts
    float* __restrict__ feats,                // [NFRM][48]
    const float* __restrict__ bn_g, const float* __restrict__ bn_b,
    const float* __restrict__ bn_m, const float* __restrict__ bn_v)
{
    __shared__ __align__(16) char smem[LDS_TOT];
    const int tid = threadIdx.x;
    const int n = blockIdx.x;
    const int lane = tid & 63, wid = tid >> 6;
    const int l15 = lane & 15, q = lane >> 4, qk = q * 8;

    // ---- zero page + stage raw frame (fp32) into weight region ----
    if (tid < 4) *(unsigned int*)(smem + ZERO_OFF + tid * 4) = 0;
    {
        const float* xf = x + (size_t)n * NPIX;
        float* sx = (float*)smem;
        for (int i = tid; i < NPIX; i += 512) sx[i] = xf[i];
    }
    __syncthreads();

    // ---- conv1 (1->48) on VALU, output bf16 into act region (swizzled) ----
    {
        const float* sx = (const float*)smem;
        for (int rnd = 0; rnd < 2; ++rnd) {
            int p = tid + rnd * 512;
            if (p < NPIX) {
                int y = p / 28, xx = p % 28;
                float a[48];
                #pragma unroll
                for (int c = 0; c < 48; ++c) a[c] = b1[c];
                #pragma unroll
                for (int dy = 0; dy < 3; ++dy) {
                    int yy = y + dy - 1;
                    if ((unsigned)yy >= 28u) continue;
                    #pragma unroll
                    for (int dx = 0; dx < 3; ++dx) {
                        int xc = xx + dx - 1;
                        if ((unsigned)xc >= 28u) continue;
                        float xv = sx[yy * 28 + xc];
                        const float* wr = w1 + (dy * 3 + dx) * 48;
                        #pragma unroll
                        for (int c = 0; c < 48; ++c) a[c] += xv * wr[c];
                    }
                }
                int base = ACT_OFF + p * 96;
                int sw = (p & 4) << 2;
                #pragma unroll
                for (int c2 = 0; c2 < 24; ++c2) {
                    unsigned int dw = (unsigned)f2bf(fmaxf(a[2 * c2], 0.f))
                                    | ((unsigned)f2bf(fmaxf(a[2 * c2 + 1], 0.f)) << 16);
                    *(unsigned int*)(smem + ((base + c2 * 4) ^ sw)) = dw;
                }
            }
        }
    }
    __syncthreads();                       // all raw-x reads done
    stage_w(smem, (const char*)wpack, tid);        // w2 -> weight region (async)
    __syncthreads();                       // drains vmem: w2 ready; conv1 act visible

    // ---- per-lane constants for the implicit-GEMM loops ----
    int tap_s[14], tpo_s[14], t96c_s[14];
    #pragma unroll
    for (int s = 0; s < 14; ++s) {
        int k = s * 32 + qk;
        int tap = k / 48;
        int kc  = k - tap * 48;
        int c16 = (kc >> 3) << 4;
        int ty = tap / 3, tx = tap - ty * 3;
        tap_s[s]  = tap;
        tpo_s[s]  = ty * 28 + tx;
        t96c_s[s] = tpo_s[s] * 96 + c16;
    }
    const int coB0 = (0 * 16 + l15) * W_CO_STRIDE + qk * 2;
    const int coB1 = (1 * 16 + l15) * W_CO_STRIDE + qk * 2;
    const int coB2 = (2 * 16 + l15) * W_CO_STRIDE + qk * 2;
    float bias2[3], bias3[3];
    #pragma unroll
    for (int nt = 0; nt < 3; ++nt) {
        bias2[nt] = b2[nt * 16 + l15];
        bias3[nt] = b3[nt * 16 + l15];
    }

    float4v acc[7][3];
    int pixb[7], pixb96[7], msk[7];
    #pragma unroll
    for (int mt = 0; mt < 7; ++mt) {
        int tt = wid + mt * 8;
        int p  = tt * 16 + l15;
        int y  = (p * 9363) >> 18;
        int x2 = p - y * 28;
        pixb[mt]   = p - 29;
        pixb96[mt] = pixb[mt] * 96;
        unsigned my0 = ((unsigned)(y - 1) < 28u) ? 0x007u : 0u;
        unsigned my1 = ((unsigned)(y    ) < 28u) ? 0x038u : 0u;
        unsigned my2 = ((unsigned)(y + 1) < 28u) ? 0x1C0u : 0u;
        unsigned mx0 = ((unsigned)(x2 - 1) < 28u) ? 0x049u : 0u;
        unsigned mx1 = ((unsigned)(x2    ) < 28u) ? 0x092u : 0u;
        unsigned mx2 = ((unsigned)(x2 + 1) < 28u) ? 0x124u : 0u;
        msk[mt] = (int)((my0 | my1 | my2) & (mx0 | mx1 | mx2));
        if (tt >= 49) msk[mt] = 0;     // pad tiles: force zero-page reads (LDS-safe)
        #pragma unroll
        for (int nt = 0; nt < 3; ++nt)
            acc[mt][nt] = (float4v){bias2[nt], bias2[nt], bias2[nt], bias2[nt]};
    }

    // ---- conv2 K-loop ----
    KLOOP(0)

    __syncthreads();                       // all act(conv1)+w2 reads done
    stage_w(smem, (const char*)wpack + WPACK_BYTES, tid);   // w3 (async)

    // write conv2 output (ReLU, bf16) into act region, overwriting conv1 act
    #pragma unroll
    for (int mt = 0; mt < 7; ++mt) {
        int tt = wid + mt * 8;
        if (tt >= 49) continue;
        #pragma unroll
        for (int nt = 0; nt < 3; ++nt) {
            int c = nt * 16 + l15;
            #pragma unroll
            for (int r = 0; r < 4; ++r) {
                int p = tt * 16 + q * 4 + r;
                unsigned short us = f2bf(fmaxf(acc[mt][nt][r], 0.f));
                unsigned int other = __shfl_xor((unsigned int)us, 1);
                if (!(l15 & 1)) {
                    unsigned int dw = (unsigned)us | (other << 16);
                    int byte = ACT_OFF + p * 96 + c * 2;
                    *(unsigned int*)(smem + (byte ^ ((p & 4) << 2))) = dw;
                }
            }
        }
    }
    __syncthreads();                       // w3 staged; act(conv2) visible

    // re-init accumulators with b3
    #pragma unroll
    for (int mt = 0; mt < 7; ++mt)
        #pragma unroll
        for (int nt = 0; nt < 3; ++nt)
            acc[mt][nt] = (float4v){bias3[nt], bias3[nt], bias3[nt], bias3[nt]};

    // ---- conv3 K-loop ----
    KLOOP(0)

    // ---- fused ReLU + global-avg-pool + BN1 ----
    float ps0 = 0.f, ps1 = 0.f, ps2 = 0.f;
    #pragma unroll
    for (int mt = 0; mt < 7; ++mt) {
        int tt = wid + mt * 8;
        if (tt >= 49) continue;
        #pragma unroll
        for (int r = 0; r < 4; ++r) {
            ps0 += fmaxf(acc[mt][0][r], 0.f);
            ps1 += fmaxf(acc[mt][1][r], 0.f);
            ps2 += fmaxf(acc[mt][2][r], 0.f);
        }
    }
    ps0 += __shfl_xor(ps0, 16); ps0 += __shfl_xor(ps0, 32);
    ps1 += __shfl_xor(ps1, 16); ps1 += __shfl_xor(ps1, 32);
    ps2 += __shfl_xor(ps2, 16); ps2 += __shfl_xor(ps2, 32);
    __syncthreads();                       // weight region now dead; alias it
    float* sRed = (float*)smem;
    if (lane < 16) {
        sRed[wid * 48 + l15]      = ps0;
        sRed[wid * 48 + 16 + l15] = ps1;
        sRed[wid * 48 + 32 + l15] = ps2;
    }
    __syncthreads();
    if (tid < 48) {
        float s = 0.f;
        #pragma unroll
        for (int wv = 0; wv < 8; ++wv) s += sRed[wv * 48 + tid];
        float r  = rsqrtf(bn_v[tid] + EPSV);
        float sc = r * bn_g[tid] * (1.0f / 784.0f);
        float sh = bn_b[tid] - bn_m[tid] * r * bn_g[tid];
        feats[(size_t)n * 48 + tid] = s * sc + sh;
    }
}

// ---------------------------------------------------------------------------
// Kernel 2: LSTM over T + BN2 + dense head. (unchanged)
// ---------------------------------------------------------------------------
__global__ __launch_bounds__(64) void lstm_kernel(
    const float* __restrict__ feats,
    const float* __restrict__ wf, const float* __restrict__ bfv,
    const float* __restrict__ wi1, const float* __restrict__ bi1,
    const float* __restrict__ wi2, const float* __restrict__ bi2,
    const float* __restrict__ wo, const float* __restrict__ bov,
    const float* __restrict__ g2, const float* __restrict__ b2v,
    const float* __restrict__ m2, const float* __restrict__ v2,
    const float* __restrict__ w_out, const float* __restrict__ b_out,
    float* __restrict__ out)
{
    __shared__ float sW[4][56][8];
    __shared__ float sBias[4][8];
    __shared__ float sZ[64];
    __shared__ float sGate[4][8];
    __shared__ float sH[8];
    __shared__ float sS[8];
    __shared__ float sK;

    int tid = threadIdx.x;
    int b = blockIdx.x;

    for (int i = tid; i < 56 * 8; i += 64) {
        (&sW[0][0][0])[i] = wf[i];
        (&sW[1][0][0])[i] = wi1[i];
        (&sW[2][0][0])[i] = wi2[i];
        (&sW[3][0][0])[i] = wo[i];
    }
    if (tid < 8) {
        sBias[0][tid] = bfv[tid];  sBias[1][tid] = bi1[tid];
        sBias[2][tid] = bi2[tid];  sBias[3][tid] = bov[tid];
        float r = rsqrtf(v2[tid] + EPSV);
        sS[tid] = r * g2[tid] * w_out[tid];
        sH[tid] = 0.0f;
    }
    if (tid == 0) {
        float k = b_out[0];
        for (int u = 0; u < 8; u++) {
            float r = rsqrtf(v2[u] + EPSV);
            k += (b2v[u] - m2[u] * r * g2[u]) * w_out[u];
        }
        sK = k;
    }
    __syncthreads();

    float c = 0.0f;
    const float* fb = feats + (size_t)b * T_ * 48;

    for (int t = 0; t < T_; t++) {
        if (tid < 48) sZ[tid] = fb[t * 48 + tid];
        else if (tid < 56) sZ[tid] = sH[tid - 48];
        __syncthreads();

        if (tid < 32) {
            int g = tid >> 3, u = tid & 7;
            float a = sBias[g][u];
            #pragma unroll
            for (int k = 0; k < 56; k++) a += sZ[k] * sW[g][k][u];
            float v = (g == 2) ? tanhf(a) : 1.0f / (1.0f + __expf(-a));
            sGate[g][u] = v;
        }
        __syncthreads();

        if (tid < 8) {
            c = sGate[0][tid] * c + sGate[1][tid] * sGate[2][tid];
            float h = sGate[3][tid] * tanhf(c);
            sH[tid] = h;
            float contrib = h * sS[tid];
            contrib += __shfl_xor(contrib, 1);
            contrib += __shfl_xor(contrib, 2);
            contrib += __shfl_xor(contrib, 4);
            if (tid == 0) out[b * T_ + t] = contrib + sK;
        }
        __syncthreads();
    }
}

// ---------------------------------------------------------------------------
extern "C" void kernel_launch(void* const* d_in, const int* in_sizes, int n_in,
                              void* d_out, int out_size, void* d_ws, size_t ws_size,
                              hipStream_t stream)
{
    const float* x    = (const float*)d_in[0];
    const float* w1   = (const float*)d_in[1];
    const float* b1   = (const float*)d_in[2];
    const float* w2   = (const float*)d_in[3];
    const float* b2   = (const float*)d_in[4];
    const float* w3   = (const float*)d_in[5];
    const float* b3   = (const float*)d_in[6];
    const float* bn1g = (const float*)d_in[7];
    const float* bn1b = (const float*)d_in[8];
    const float* bn1m = (const float*)d_in[9];
    const float* bn1v = (const float*)d_in[10];
    const float* wf   = (const float*)d_in[11];
    const float* bf   = (const float*)d_in[12];
    const float* wi1  = (const float*)d_in[13];
    const float* bi1  = (const float*)d_in[14];
    const float* wi2  = (const float*)d_in[15];
    const float* bi2  = (const float*)d_in[16];
    const float* wo   = (const float*)d_in[17];
    const float* bo   = (const float*)d_in[18];
    const float* bn2g = (const float*)d_in[19];
    const float* bn2b = (const float*)d_in[20];
    const float* bn2m = (const float*)d_in[21];
    const float* bn2v = (const float*)d_in[22];
    const float* wout = (const float*)d_in[23];
    const float* bout = (const float*)d_in[24];

    unsigned short* wpack = (unsigned short*)d_ws;              // 2*88064 B
    float* feats = (float*)((char*)d_ws + 2 * WPACK_BYTES);     // 1024*48 fp32
    const size_t need = 2 * WPACK_BYTES + (size_t)NFRM * 48 * 4;
    if (ws_size < need) return;

    pack_weights<<<(2 * 44032) / 256, 256, 0, stream>>>(w2, w3, wpack);
    fused_cnn<<<NFRM, 512, 0, stream>>>(x, w1, b1, b2, b3, wpack, feats,
                                        bn1g, bn1b, bn1m, bn1v);
    lstm_kernel<<<B_, 64, 0, stream>>>(feats, wf, bf, wi1, bi1, wi2, bi2, wo, bo,
                                       bn2g, bn2b, bn2m, bn2v, wout, bout,
                                       (float*)d_out);
}

// Round 4
// 125.983 us; speedup vs baseline: 18.4854x; 1.5180x over previous
//
#include <hip/hip_runtime.h>
#include <stdint.h>

#define B_ 32
#define T_ 32
#define NPIX 784
#define NFRM 1024
#define EPSV 1e-3f

typedef __attribute__((ext_vector_type(8))) _Float16 half8v;
typedef __attribute__((ext_vector_type(4))) float float4v;

// ---- LDS map (bytes) ----
// W region   [0, 43008)        : fp16 weight pack [14 s][4 q][48 co][8 k] (16B frags)
// x region   [43008, 46144)    : raw frame fp32 (784*4)
// act region [46144, 121600)   : fp16 acts, 6 cb * 12576 B; chunk = (cb, pixel) 16B
//                                addr = ACT_OFF + cb*12576 + pixel*16  (pixel stride 16B
//                                => consecutive lanes read contiguous => conflict-free;
//                                cb stride 12576 = 8-bank stagger for the writeback)
// zero page  [121600, 121616)
#define W_BYTES  43008
#define X_OFF    43008
#define ACT_OFF  46144
#define CB_STRIDE 12576
#define ZERO_OFF (ACT_OFF + 6 * CB_STRIDE)   // 121600
#define LDS_TOT  (ZERO_OFF + 16)             // 121616

__device__ __forceinline__ unsigned short f2h(float f) {
    union { _Float16 h; unsigned short u; } cv; cv.h = (_Float16)f; return cv.u;
}

// ---------------------------------------------------------------------------
// Kernel 0: pack w2/w3 as fp16 in MFMA-B fragment order [s][q][co][j].
// k = s*32 + q*8 + j = tap*48 + cin ; k >= 432 zero-padded.
// ---------------------------------------------------------------------------
__global__ __launch_bounds__(256) void pack_weights(
    const float* __restrict__ w2, const float* __restrict__ w3,
    unsigned short* __restrict__ out)
{
    int idx = blockIdx.x * 256 + threadIdx.x;     // 0 .. 43007
    int conv = idx / 21504;
    int r = idx - conv * 21504;
    const float* w = conv ? w3 : w2;
    int s  = r / 1536;
    int r2 = r - s * 1536;
    int q  = r2 / 384;
    int r3 = r2 - q * 384;
    int co = r3 >> 3, j = r3 & 7;
    int k  = s * 32 + q * 8 + j;
    unsigned short v = 0;
    if (k < 432) v = f2h(w[k * 48 + co]);
    out[idx] = v;
}

// async stage of one 43008-B weight pack, global -> LDS W region (linear)
__device__ __forceinline__ void stage_w(char* smem, const char* g, int tid) {
    int lane = tid & 63, wid = tid >> 6;
    const char* gl = g + lane * 16;
    for (int c = wid; c < 42; c += 8) {
        int off = c * 1024;
        __builtin_amdgcn_global_load_lds(
            (const __attribute__((address_space(1))) unsigned int*)(gl + off),
            (__attribute__((address_space(3))) unsigned int*)(smem + off),
            16, 0, 0);
    }
}

// ---------------------------------------------------------------------------
// Fused conv1 + conv2 + conv3 (fp16 MFMA single-pass) + ReLU + avgpool + BN1.
// One block = one frame; 512 threads = 8 waves; wave w owns M-tiles {w, w+8,..}
// (49 real 16-pixel tiles; 784 = 49*16 exactly).
// ---------------------------------------------------------------------------
#define KLOOP                                                                  \
    _Pragma("unroll")                                                          \
    for (int s = 0; s < 14; ++s) {                                             \
        const char* wb = smem + bB + s * 3072;                                 \
        half8v bv0 = *(const half8v*)(wb);                                     \
        half8v bv1 = *(const half8v*)(wb + 256);                               \
        half8v bv2 = *(const half8v*)(wb + 512);                               \
        _Pragma("unroll")                                                      \
        for (int mt = 0; mt < 7; ++mt) {                                       \
            int ad = pixb16[mt] + aoff_s[s];                                   \
            ad = ((msk[mt] >> tap_s[s]) & 1) ? ad : ZERO_OFF;                  \
            half8v a = *(const half8v*)(smem + ad);                            \
            acc[mt][0] = __builtin_amdgcn_mfma_f32_16x16x32_f16(a, bv0, acc[mt][0], 0, 0, 0); \
            acc[mt][1] = __builtin_amdgcn_mfma_f32_16x16x32_f16(a, bv1, acc[mt][1], 0, 0, 0); \
            acc[mt][2] = __builtin_amdgcn_mfma_f32_16x16x32_f16(a, bv2, acc[mt][2], 0, 0, 0); \
        }                                                                      \
    }

__global__ __launch_bounds__(512, 1) void fused_cnn(
    const float* __restrict__ x,              // [NFRM][784] fp32
    const float* __restrict__ w1, const float* __restrict__ b1,
    const float* __restrict__ b2, const float* __restrict__ b3,
    const unsigned short* __restrict__ wpack, // [2][21504] halfs
    float* __restrict__ feats,                // [NFRM][48]
    const float* __restrict__ bn_g, const float* __restrict__ bn_b,
    const float* __restrict__ bn_m, const float* __restrict__ bn_v)
{
    __shared__ __align__(16) char smem[LDS_TOT];
    const int tid = threadIdx.x;
    const int n = blockIdx.x;
    const int lane = tid & 63, wid = tid >> 6;
    const int l15 = lane & 15, q = lane >> 4;

    // zero page + w2 (async) + raw frame
    if (tid < 4) *(unsigned int*)(smem + ZERO_OFF + tid * 4) = 0;
    stage_w(smem, (const char*)wpack, tid);
    {
        const float* xf = x + (size_t)n * NPIX;
        float* sx = (float*)(smem + X_OFF);
        for (int i = tid; i < NPIX; i += 512) sx[i] = xf[i];
    }
    __syncthreads();                   // x visible; w2 drained (vmcnt 0 at barrier)

    // ---- conv1 (1->48) on VALU, fp16 chunks into act region ----
    {
        const float* sx = (const float*)(smem + X_OFF);
        for (int rnd = 0; rnd < 2; ++rnd) {
            int p = tid + rnd * 512;
            if (p < NPIX) {
                int y = p / 28, xx = p % 28;
                float a[48];
                #pragma unroll
                for (int c = 0; c < 48; ++c) a[c] = b1[c];
                #pragma unroll
                for (int dy = 0; dy < 3; ++dy) {
                    int yy = y + dy - 1;
                    if ((unsigned)yy >= 28u) continue;
                    #pragma unroll
                    for (int dx = 0; dx < 3; ++dx) {
                        int xc = xx + dx - 1;
                        if ((unsigned)xc >= 28u) continue;
                        float xv = sx[yy * 28 + xc];
                        const float* wr = w1 + (dy * 3 + dx) * 48;
                        #pragma unroll
                        for (int c = 0; c < 48; ++c) a[c] += xv * wr[c];
                    }
                }
                #pragma unroll
                for (int cb = 0; cb < 6; ++cb) {
                    half8v h;
                    #pragma unroll
                    for (int j = 0; j < 8; ++j)
                        h[j] = (_Float16)fmaxf(a[cb * 8 + j], 0.f);
                    *(half8v*)(smem + ACT_OFF + cb * CB_STRIDE + p * 16) = h;
                }
            }
        }
    }
    __syncthreads();

    // ---- per-lane constants ----
    int tap_s[14], aoff_s[14];
    #pragma unroll
    for (int s = 0; s < 14; ++s) {
        int k = s * 32 + q * 8;
        int tap = k / 48;              // constant over j in [0,8): 8 | 48
        int kc  = k - tap * 48;        // 0,8,...,40
        int ty = tap / 3, tx = tap - ty * 3;
        tap_s[s]  = tap;
        aoff_s[s] = ACT_OFF + (kc >> 3) * CB_STRIDE + (ty * 28 + tx) * 16;
    }
    const int bB = q * 768 + l15 * 16;         // B frag base (W region at 0)
    float bias2[3], bias3[3];
    #pragma unroll
    for (int nt = 0; nt < 3; ++nt) {
        bias2[nt] = b2[nt * 16 + l15];
        bias3[nt] = b3[nt * 16 + l15];
    }

    float4v acc[7][3];
    int pixb16[7], msk[7];
    #pragma unroll
    for (int mt = 0; mt < 7; ++mt) {
        int tt = wid + mt * 8;
        int p  = tt * 16 + l15;
        int y  = (p * 9363) >> 18;             // p/28 (valid p<=895)
        int x2 = p - y * 28;
        pixb16[mt] = (p - 29) * 16;
        unsigned my0 = ((unsigned)(y - 1) < 28u) ? 0x007u : 0u;
        unsigned my1 = ((unsigned)(y    ) < 28u) ? 0x038u : 0u;
        unsigned my2 = ((unsigned)(y + 1) < 28u) ? 0x1C0u : 0u;
        unsigned mx0 = ((unsigned)(x2 - 1) < 28u) ? 0x049u : 0u;
        unsigned mx1 = ((unsigned)(x2    ) < 28u) ? 0x092u : 0u;
        unsigned mx2 = ((unsigned)(x2 + 1) < 28u) ? 0x124u : 0u;
        msk[mt] = (int)((my0 | my1 | my2) & (mx0 | mx1 | mx2));
        if (tt >= 49) msk[mt] = 0;             // pad tiles -> zero page only
        #pragma unroll
        for (int nt = 0; nt < 3; ++nt)
            acc[mt][nt] = (float4v){bias2[nt], bias2[nt], bias2[nt], bias2[nt]};
    }

    // ---- conv2 ----
    KLOOP

    __syncthreads();                           // conv1-act + w2 reads done
    stage_w(smem, (const char*)wpack + W_BYTES, tid);   // w3 (async)

    // conv2 output (ReLU, fp16) -> act region, 2B stores (2-way max via cb stagger)
    #pragma unroll
    for (int mt = 0; mt < 7; ++mt) {
        int tt = wid + mt * 8;
        if (tt >= 49) continue;
        #pragma unroll
        for (int nt = 0; nt < 3; ++nt) {
            int c = nt * 16 + l15;
            char* base = smem + ACT_OFF + (c >> 3) * CB_STRIDE + (c & 7) * 2;
            #pragma unroll
            for (int r = 0; r < 4; ++r) {
                int p = tt * 16 + q * 4 + r;
                *(unsigned short*)(base + p * 16) = f2h(fmaxf(acc[mt][nt][r], 0.f));
            }
        }
    }
    __syncthreads();                           // w3 staged; conv2 act visible

    #pragma unroll
    for (int mt = 0; mt < 7; ++mt)
        #pragma unroll
        for (int nt = 0; nt < 3; ++nt)
            acc[mt][nt] = (float4v){bias3[nt], bias3[nt], bias3[nt], bias3[nt]};

    // ---- conv3 ----
    KLOOP

    // ---- fused ReLU + global-avg-pool + BN1 ----
    float ps0 = 0.f, ps1 = 0.f, ps2 = 0.f;
    #pragma unroll
    for (int mt = 0; mt < 7; ++mt) {
        int tt = wid + mt * 8;
        if (tt >= 49) continue;
        #pragma unroll
        for (int r = 0; r < 4; ++r) {
            ps0 += fmaxf(acc[mt][0][r], 0.f);
            ps1 += fmaxf(acc[mt][1][r], 0.f);
            ps2 += fmaxf(acc[mt][2][r], 0.f);
        }
    }
    ps0 += __shfl_xor(ps0, 16); ps0 += __shfl_xor(ps0, 32);
    ps1 += __shfl_xor(ps1, 16); ps1 += __shfl_xor(ps1, 32);
    ps2 += __shfl_xor(ps2, 16); ps2 += __shfl_xor(ps2, 32);
    __syncthreads();                           // W region dead; alias as reduce buf
    float* sRed = (float*)smem;
    if (lane < 16) {
        sRed[wid * 48 + l15]      = ps0;
        sRed[wid * 48 + 16 + l15] = ps1;
        sRed[wid * 48 + 32 + l15] = ps2;
    }
    __syncthreads();
    if (tid < 48) {
        float s = 0.f;
        #pragma unroll
        for (int wv = 0; wv < 8; ++wv) s += sRed[wv * 48 + tid];
        float r  = rsqrtf(bn_v[tid] + EPSV);
        float sc = r * bn_g[tid] * (1.0f / 784.0f);
        float sh = bn_b[tid] - bn_m[tid] * r * bn_g[tid];
        feats[(size_t)n * 48 + tid] = s * sc + sh;
    }
}

// ---------------------------------------------------------------------------
// Kernel 2: LSTM over T + BN2 + dense head. (unchanged)
// ---------------------------------------------------------------------------
__global__ __launch_bounds__(64) void lstm_kernel(
    const float* __restrict__ feats,
    const float* __restrict__ wf, const float* __restrict__ bfv,
    const float* __restrict__ wi1, const float* __restrict__ bi1,
    const float* __restrict__ wi2, const float* __restrict__ bi2,
    const float* __restrict__ wo, const float* __restrict__ bov,
    const float* __restrict__ g2, const float* __restrict__ b2v,
    const float* __restrict__ m2, const float* __restrict__ v2,
    const float* __restrict__ w_out, const float* __restrict__ b_out,
    float* __restrict__ out)
{
    __shared__ float sW[4][56][8];
    __shared__ float sBias[4][8];
    __shared__ float sZ[64];
    __shared__ float sGate[4][8];
    __shared__ float sH[8];
    __shared__ float sS[8];
    __shared__ float sK;

    int tid = threadIdx.x;
    int b = blockIdx.x;

    for (int i = tid; i < 56 * 8; i += 64) {
        (&sW[0][0][0])[i] = wf[i];
        (&sW[1][0][0])[i] = wi1[i];
        (&sW[2][0][0])[i] = wi2[i];
        (&sW[3][0][0])[i] = wo[i];
    }
    if (tid < 8) {
        sBias[0][tid] = bfv[tid];  sBias[1][tid] = bi1[tid];
        sBias[2][tid] = bi2[tid];  sBias[3][tid] = bov[tid];
        float r = rsqrtf(v2[tid] + EPSV);
        sS[tid] = r * g2[tid] * w_out[tid];
        sH[tid] = 0.0f;
    }
    if (tid == 0) {
        float k = b_out[0];
        for (int u = 0; u < 8; u++) {
            float r = rsqrtf(v2[u] + EPSV);
            k += (b2v[u] - m2[u] * r * g2[u]) * w_out[u];
        }
        sK = k;
    }
    __syncthreads();

    float c = 0.0f;
    const float* fb = feats + (size_t)b * T_ * 48;

    for (int t = 0; t < T_; t++) {
        if (tid < 48) sZ[tid] = fb[t * 48 + tid];
        else if (tid < 56) sZ[tid] = sH[tid - 48];
        __syncthreads();

        if (tid < 32) {
            int g = tid >> 3, u = tid & 7;
            float a = sBias[g][u];
            #pragma unroll
            for (int k = 0; k < 56; k++) a += sZ[k] * sW[g][k][u];
            float v = (g == 2) ? tanhf(a) : 1.0f / (1.0f + __expf(-a));
            sGate[g][u] = v;
        }
        __syncthreads();

        if (tid < 8) {
            c = sGate[0][tid] * c + sGate[1][tid] * sGate[2][tid];
            float h = sGate[3][tid] * tanhf(c);
            sH[tid] = h;
            float contrib = h * sS[tid];
            contrib += __shfl_xor(contrib, 1);
            contrib += __shfl_xor(contrib, 2);
            contrib += __shfl_xor(contrib, 4);
            if (tid == 0) out[b * T_ + t] = contrib + sK;
        }
        __syncthreads();
    }
}

// ---------------------------------------------------------------------------
extern "C" void kernel_launch(void* const* d_in, const int* in_sizes, int n_in,
                              void* d_out, int out_size, void* d_ws, size_t ws_size,
                              hipStream_t stream)
{
    const float* x    = (const float*)d_in[0];
    const float* w1   = (const float*)d_in[1];
    const float* b1   = (const float*)d_in[2];
    const float* w2   = (const float*)d_in[3];
    const float* b2   = (const float*)d_in[4];
    const float* w3   = (const float*)d_in[5];
    const float* b3   = (const float*)d_in[6];
    const float* bn1g = (const float*)d_in[7];
    const float* bn1b = (const float*)d_in[8];
    const float* bn1m = (const float*)d_in[9];
    const float* bn1v = (const float*)d_in[10];
    const float* wf   = (const float*)d_in[11];
    const float* bf   = (const float*)d_in[12];
    const float* wi1  = (const float*)d_in[13];
    const float* bi1  = (const float*)d_in[14];
    const float* wi2  = (const float*)d_in[15];
    const float* bi2  = (const float*)d_in[16];
    const float* wo   = (const float*)d_in[17];
    const float* bo   = (const float*)d_in[18];
    const float* bn2g = (const float*)d_in[19];
    const float* bn2b = (const float*)d_in[20];
    const float* bn2m = (const float*)d_in[21];
    const float* bn2v = (const float*)d_in[22];
    const float* wout = (const float*)d_in[23];
    const float* bout = (const float*)d_in[24];

    unsigned short* wpack = (unsigned short*)d_ws;            // 2*43008 B
    float* feats = (float*)((char*)d_ws + 2 * W_BYTES);       // 1024*48 fp32
    const size_t need = 2 * W_BYTES + (size_t)NFRM * 48 * 4;
    if (ws_size < need) return;

    pack_weights<<<168, 256, 0, stream>>>(w2, w3, wpack);
    fused_cnn<<<NFRM, 512, 0, stream>>>(x, w1, b1, b2, b3, wpack, feats,
                                        bn1g, bn1b, bn1m, bn1v);
    lstm_kernel<<<B_, 64, 0, stream>>>(feats, wf, bf, wi1, bi1, wi2, bi2, wo, bo,
                                       bn2g, bn2b, bn2m, bn2v, wout, bout,
                                       (float*)d_out);
}